// Round 17
// baseline (281.661 us; speedup 1.0000x reference)
//
#include <hip/hip_runtime.h>
#include <hip/hip_bf16.h>
#include <cstdint>
#include <cstddef>

#define NGRAPH 64
#define NPG0   1024
#define NNODE  65536     // NGRAPH*NPG0
#define NEDGE  524288
#define EPG    8192      // NEDGE/NGRAPH
#define DIM    128
#define RCHUNK 16        // readout partial chunks per graph
#define PSTRIDE ((size_t)NGRAPH * RCHUNK * 128)
#define AROWS  64        // rows per k_agg_gemm block (2 tiles per wave)

typedef __attribute__((ext_vector_type(8))) short short8v;   // 8 bf16
typedef __attribute__((ext_vector_type(4))) float f32x4;

__device__ __forceinline__ unsigned bf16rne(float f) {
  unsigned u = __float_as_uint(f);
  return (u + 0x7FFFu + ((u >> 16) & 1u)) >> 16;
}
__device__ __forceinline__ unsigned pack2bf(float a, float b) {
  return bf16rne(a) | (bf16rne(b) << 16);
}
__device__ __forceinline__ float bf_lo(unsigned u) { return __uint_as_float(u << 16); }
__device__ __forceinline__ float bf_hi(unsigned u) { return __uint_as_float(u & 0xffff0000u); }

__device__ __forceinline__ void add8(float* a, uint4 u) {
  a[0] += bf_lo(u.x); a[1] += bf_hi(u.x);
  a[2] += bf_lo(u.y); a[3] += bf_hi(u.y);
  a[4] += bf_lo(u.z); a[5] += bf_hi(u.z);
  a[6] += bf_lo(u.w); a[7] += bf_hi(u.w);
}

// ---------------- gather x_bf = bf16(emb[node_idx]) ----------------
__global__ __launch_bounds__(256) void k_gather(const float* __restrict__ emb,
    const int* __restrict__ nid, unsigned short* __restrict__ xbf)
{
  int tid = blockIdx.x * 256 + threadIdx.x;
  int i = tid >> 5, lane = tid & 31;
  int row = nid[i];
  float4 v = ((const float4*)(emb + (size_t)row * DIM))[lane];
  uint2 u;
  u.x = pack2bf(v.x, v.y);
  u.y = pack2bf(v.z, v.w);
  ((uint2*)xbf)[(size_t)i * 32 + lane] = u;
}

// ---------------- 1/||pool_w|| ----------------
__global__ __launch_bounds__(64) void k_norm(const float* __restrict__ pw,
    float* __restrict__ inv_norm)
{
  int t = threadIdx.x;
  float a = pw[t], b = pw[t + 64];
  float v = a * a + b * b;
  for (int off = 32; off; off >>= 1) v += __shfl_xor(v, off);
  if (t == 0) *inv_norm = 1.0f / sqrtf(v);
}

// ------- pre-swizzle weights into MFMA B-fragment layout, bf16 hi/lo ------
__global__ __launch_bounds__(256) void k_prep_wfrag(
    const float* __restrict__ w1l, const float* __restrict__ w1r,
    const float* __restrict__ w2l, const float* __restrict__ w2r,
    short* __restrict__ whiF, short* __restrict__ wloF)
{
  int id = blockIdx.x * 256 + threadIdx.x;    // 0..65535 (2 sets x 32768)
  int set = id >> 15;
  int r = id & 32767;
  int j  = r & 7;
  int l  = (r >> 3) & 63;
  int nt = (r >> 9) & 7;
  int kk = r >> 12;
  int k = kk * 32 + ((l >> 4) & 3) * 8 + j;
  int n = nt * 16 + (l & 15);
  const float* wl = set ? w2l : w1l;
  const float* wr = set ? w2r : w1r;
  float w = (k < 128) ? wl[n * 128 + k] : wr[n * 128 + (k - 128)];
  unsigned hb = bf16rne(w);
  float hif = __uint_as_float(hb << 16);
  unsigned lb = bf16rne(w - hif);
  whiF[id] = (short)hb;
  wloF[id] = (short)lb;
}

// ---------------- stage-0 CSR build straight from edge_idx ----------------
__global__ __launch_bounds__(1024) void k_csr0(const int* __restrict__ ei,
    int* __restrict__ off_g, int* __restrict__ elist_g, float* __restrict__ c_out)
{
  __shared__ int cnt[1024];
  __shared__ int cur[1024];
  __shared__ int wsum[16];
  const int t = threadIdx.x, g = blockIdx.x;
  const int nodeBase = g * NPG0;
  const int e0 = g * EPG;
  cnt[t] = 0;
  __syncthreads();
  int sv8[8], dl8[8];
  #pragma unroll
  for (int i = 0; i < 8; ++i) {
    int e = e0 + t + i * 1024;
    sv8[i] = ei[e];
    dl8[i] = ei[NEDGE + e] - nodeBase;
    atomicAdd(&cnt[dl8[i]], 1);
  }
  __syncthreads();
  const int lane = t & 63, w = t >> 6;
  int cv = cnt[t];
  int x = cv;
  #pragma unroll
  for (int off = 1; off < 64; off <<= 1) {
    int y = __shfl_up(x, off);
    if (lane >= off) x += y;
  }
  if (lane == 63) wsum[w] = x;
  __syncthreads();
  if (t < 16) {
    int v = wsum[t];
    #pragma unroll
    for (int off2 = 1; off2 < 16; off2 <<= 1) {
      int y = __shfl_up(v, off2);
      if (t >= off2) v += y;
    }
    wsum[t] = v;
  }
  __syncthreads();
  int incl = x + (w ? wsum[w - 1] : 0);
  int excl = incl - cv;
  cur[t] = excl;
  int* offp = off_g + g * 1025;
  offp[t] = excl;
  if (t == 1023) offp[1024] = incl;
  c_out[nodeBase + t] = (float)cv;
  __syncthreads();
  int* elp = elist_g + g * EPG;
  #pragma unroll
  for (int i = 0; i < 8; ++i) {
    int pos = atomicAdd(&cur[dl8[i]], 1);
    elp[pos] = sv8[i];
  }
}

// ------- FUSED aggregate + MFMA SAGE layer (64 rows, 2 tiles/wave) --------
// blockIdx = slice*64 + g ; 128 threads. Each wave computes TWO 16-row MFMA
// tiles from ONE weight-fragment read stream (halves weight L2 traffic).
__global__ __launch_bounds__(128) void k_agg_gemm(
    const int* __restrict__ off_g, const int* __restrict__ elist_g,
    const unsigned short* __restrict__ xbf, unsigned short* __restrict__ hbf,
    const short* __restrict__ whiF, const short* __restrict__ wloF,
    const float* __restrict__ bl, const float* __restrict__ pw,
    float* __restrict__ score, int npg)
{
  __shared__ float sA[AROWS * 128];   // 32 KB f32 aggregate tile, XOR swizzle
  __shared__ float cntA[AROWS];
  const int g     = blockIdx.x & 63;
  const int slice = blockIdx.x >> 6;
  const int nodeBase = g * npg;
  const int vbase = slice * AROWS;
  const int t = threadIdx.x;
  float4* sA4 = (float4*)sA;
  const uint4* xb4 = (const uint4*)xbf;   // 16 uint4 per row

  // ---- phase A: 4 groups x 32 lanes, 16 rows each (two-row interleave) ----
  {
    const int gr = t >> 5, l32 = t & 31;
    const int lh = l32 & 15;           // uint4 slot within row
    const int half = l32 >> 4;         // 0: even edge, 1: odd edge
    const int* off = off_g + g * 1025;
    const int* el  = elist_g + g * EPG;
    #pragma unroll
    for (int ip = 0; ip < 8; ++ip) {
      const int vbA = gr * 16 + ip * 2, vbB = vbA + 1;
      const int vA = vbase + vbA, vB = vbase + vbB;
      float accA[8] = {0,0,0,0,0,0,0,0}, accB[8] = {0,0,0,0,0,0,0,0};
      int eA = 0, endA = 0, eB = 0, endB = 0;
      if (vA < npg) { eA = off[vA]; endA = off[vA + 1]; }
      if (vB < npg) { eB = off[vB]; endB = off[vB + 1]; }
      const int cnA = endA - eA, cnB = endB - eB;
      while (eA + 4 <= endA && eB + 4 <= endB) {
        int ia0 = el[eA + half],     ia1 = el[eA + 2 + half];
        int ib0 = el[eB + half],     ib1 = el[eB + 2 + half];
        uint4 ua0 = xb4[(size_t)ia0 * 16 + lh];
        uint4 ua1 = xb4[(size_t)ia1 * 16 + lh];
        uint4 ub0 = xb4[(size_t)ib0 * 16 + lh];
        uint4 ub1 = xb4[(size_t)ib1 * 16 + lh];
        add8(accA, ua0); add8(accA, ua1);
        add8(accB, ub0); add8(accB, ub1);
        eA += 4; eB += 4;
      }
      while (eA + 2 <= endA) {
        uint4 u = xb4[(size_t)el[eA + half] * 16 + lh];
        add8(accA, u);
        eA += 2;
      }
      if (eA < endA && half == 0) {
        uint4 u = xb4[(size_t)el[eA] * 16 + lh];
        add8(accA, u);
      }
      while (eB + 2 <= endB) {
        uint4 u = xb4[(size_t)el[eB + half] * 16 + lh];
        add8(accB, u);
        eB += 2;
      }
      if (eB < endB && half == 0) {
        uint4 u = xb4[(size_t)el[eB] * 16 + lh];
        add8(accB, u);
      }
      #pragma unroll
      for (int j = 0; j < 8; ++j) {
        accA[j] += __shfl_xor(accA[j], 16);
        accB[j] += __shfl_xor(accB[j], 16);
      }
      if (half == 0) {
        float4 a0 = {accA[0], accA[1], accA[2], accA[3]};
        float4 a1 = {accA[4], accA[5], accA[6], accA[7]};
        float4 b0 = {accB[0], accB[1], accB[2], accB[3]};
        float4 b1 = {accB[4], accB[5], accB[6], accB[7]};
        sA4[vbA * 32 + ((2 * lh + 0) ^ (vbA & 7))] = a0;
        sA4[vbA * 32 + ((2 * lh + 1) ^ (vbA & 7))] = a1;
        sA4[vbB * 32 + ((2 * lh + 0) ^ (vbB & 7))] = b0;
        sA4[vbB * 32 + ((2 * lh + 1) ^ (vbB & 7))] = b1;
      }
      if (l32 == 0) { cntA[vbA] = (float)cnA; cntA[vbB] = (float)cnB; }
    }
  }
  __syncthreads();

  // ---- phase B: MFMA GEMM, 2 tiles per wave sharing weight reads ----
  const int wv = t >> 6, l = t & 63;
  const int lrow = l & 15, lk = l >> 4;       // lk 0..3
  const int rowb0 = wv * 32 + lrow;           // tile 0 row in block
  const int rowb1 = rowb0 + 16;               // tile 1 row in block
  const int rsw0 = rowb0 & 7, rsw1 = rowb1 & 7;
  const int rowg0 = nodeBase + min(vbase + rowb0, npg - 1);
  const int rowg1 = nodeBase + min(vbase + rowb1, npg - 1);
  const float invc0 = 1.0f / fmaxf(cntA[rowb0], 1.0f);
  const float invc1 = 1.0f / fmaxf(cntA[rowb1], 1.0f);
  f32x4 acc0[8], acc1[8];
  #pragma unroll
  for (int nt = 0; nt < 8; ++nt) {
    acc0[nt] = (f32x4){0.f, 0.f, 0.f, 0.f};
    acc1[nt] = (f32x4){0.f, 0.f, 0.f, 0.f};
  }
  const float4* sArow0 = sA4 + rowb0 * 32;
  const float4* sArow1 = sA4 + rowb1 * 32;
  const uint4* xrow0 = (const uint4*)xbf + (size_t)rowg0 * 16;
  const uint4* xrow1 = (const uint4*)xbf + (size_t)rowg1 * 16;
  const short8v* bh = (const short8v*)whiF;
  const short8v* bo = (const short8v*)wloF;

  #pragma unroll
  for (int kk = 0; kk < 8; ++kk) {
    short8v a0hi, a0lo, a1hi, a1lo;
    bool self16 = (kk >= 4);
    if (!self16) {
      int sbase = kk * 8 + lk * 2;
      float4 p0 = sArow0[(sbase + 0) ^ rsw0];
      float4 p1 = sArow0[(sbase + 1) ^ rsw0];
      float4 q0 = sArow1[(sbase + 0) ^ rsw1];
      float4 q1 = sArow1[(sbase + 1) ^ rsw1];
      float av0[8] = { p0.x*invc0, p0.y*invc0, p0.z*invc0, p0.w*invc0,
                       p1.x*invc0, p1.y*invc0, p1.z*invc0, p1.w*invc0 };
      float av1[8] = { q0.x*invc1, q0.y*invc1, q0.z*invc1, q0.w*invc1,
                       q1.x*invc1, q1.y*invc1, q1.z*invc1, q1.w*invc1 };
      #pragma unroll
      for (int j = 0; j < 8; ++j) {
        unsigned hb0 = bf16rne(av0[j]);
        a0hi[j] = (short)hb0;
        a0lo[j] = (short)bf16rne(av0[j] - __uint_as_float(hb0 << 16));
        unsigned hb1 = bf16rne(av1[j]);
        a1hi[j] = (short)hb1;
        a1lo[j] = (short)bf16rne(av1[j] - __uint_as_float(hb1 << 16));
      }
    } else {
      uint4 u0 = xrow0[(kk - 4) * 4 + lk];
      uint4 u1 = xrow1[(kk - 4) * 4 + lk];
      a0hi[0] = (short)(u0.x & 0xffff); a0hi[1] = (short)(u0.x >> 16);
      a0hi[2] = (short)(u0.y & 0xffff); a0hi[3] = (short)(u0.y >> 16);
      a0hi[4] = (short)(u0.z & 0xffff); a0hi[5] = (short)(u0.z >> 16);
      a0hi[6] = (short)(u0.w & 0xffff); a0hi[7] = (short)(u0.w >> 16);
      a1hi[0] = (short)(u1.x & 0xffff); a1hi[1] = (short)(u1.x >> 16);
      a1hi[2] = (short)(u1.y & 0xffff); a1hi[3] = (short)(u1.y >> 16);
      a1hi[4] = (short)(u1.z & 0xffff); a1hi[5] = (short)(u1.z >> 16);
      a1hi[6] = (short)(u1.w & 0xffff); a1hi[7] = (short)(u1.w >> 16);
    }
    #pragma unroll
    for (int nt = 0; nt < 8; ++nt) {
      int fi = (kk * 8 + nt) * 64 + l;
      short8v bhi = bh[fi];
      short8v blo = bo[fi];
      acc0[nt] = __builtin_amdgcn_mfma_f32_16x16x32_bf16(a0hi, bhi, acc0[nt], 0, 0, 0);
      acc1[nt] = __builtin_amdgcn_mfma_f32_16x16x32_bf16(a1hi, bhi, acc1[nt], 0, 0, 0);
      if (!self16) {
        acc0[nt] = __builtin_amdgcn_mfma_f32_16x16x32_bf16(a0lo, bhi, acc0[nt], 0, 0, 0);
        acc1[nt] = __builtin_amdgcn_mfma_f32_16x16x32_bf16(a1lo, bhi, acc1[nt], 0, 0, 0);
      }
      acc0[nt] = __builtin_amdgcn_mfma_f32_16x16x32_bf16(a0hi, blo, acc0[nt], 0, 0, 0);
      acc1[nt] = __builtin_amdgcn_mfma_f32_16x16x32_bf16(a1hi, blo, acc1[nt], 0, 0, 0);
    }
  }

  // epilogue for both tiles: bias + relu + store + fused pool score
  #pragma unroll
  for (int s = 0; s < 2; ++s) {
    f32x4* acc = s ? acc1 : acc0;
    const int mbv = vbase + wv * 32 + s * 16 + lk * 4;
    float sp0 = 0.f, sp1 = 0.f, sp2 = 0.f, sp3 = 0.f;
    #pragma unroll
    for (int nt = 0; nt < 8; ++nt) {
      int col = nt * 16 + lrow;
      float bb = bl[col], pv = pw[col];
      float h0 = fmaxf(acc[nt][0] + bb, 0.f);
      float h1 = fmaxf(acc[nt][1] + bb, 0.f);
      float h2 = fmaxf(acc[nt][2] + bb, 0.f);
      float h3 = fmaxf(acc[nt][3] + bb, 0.f);
      if (mbv + 0 < npg) hbf[(size_t)(nodeBase + mbv + 0) * DIM + col] = (unsigned short)bf16rne(h0);
      if (mbv + 1 < npg) hbf[(size_t)(nodeBase + mbv + 1) * DIM + col] = (unsigned short)bf16rne(h1);
      if (mbv + 2 < npg) hbf[(size_t)(nodeBase + mbv + 2) * DIM + col] = (unsigned short)bf16rne(h2);
      if (mbv + 3 < npg) hbf[(size_t)(nodeBase + mbv + 3) * DIM + col] = (unsigned short)bf16rne(h3);
      sp0 += h0 * pv; sp1 += h1 * pv; sp2 += h2 * pv; sp3 += h3 * pv;
    }
    #pragma unroll
    for (int off = 1; off <= 8; off <<= 1) {
      sp0 += __shfl_xor(sp0, off);
      sp1 += __shfl_xor(sp1, off);
      sp2 += __shfl_xor(sp2, off);
      sp3 += __shfl_xor(sp3, off);
    }
    if (lrow == 0) {
      if (mbv + 0 < npg) score[nodeBase + mbv + 0] = sp0;
      if (mbv + 1 < npg) score[nodeBase + mbv + 1] = sp1;
      if (mbv + 2 < npg) score[nodeBase + mbv + 2] = sp2;
      if (mbv + 3 < npg) score[nodeBase + mbv + 3] = sp3;
    }
  }
}

// ------- fused: shuffle-bitonic top-k + relabel + build next CSR ----------
__global__ __launch_bounds__(1024) void k_topk_fused(
    const float* __restrict__ score, const float* __restrict__ inv_norm_p,
    int npg, int k, int* __restrict__ sel_pos, float* __restrict__ sel_scale,
    int build_next, int write_eout,
    const int* __restrict__ ein_src, const int* __restrict__ ein_dst,
    int* __restrict__ eout_src, int* __restrict__ eout_dst,
    int* __restrict__ off_g, int* __restrict__ elist_g, float* __restrict__ c_out)
{
  __shared__ float key[1024];
  __shared__ int   idxs[1024];
  __shared__ int   nid[1024];
  __shared__ int   cnt[1024];
  __shared__ int   cur[1024];
  __shared__ int   wsum[16];
  const int t = threadIdx.x, g = blockIdx.x;
  const int base = g * npg;
  float rk = (t < npg) ? score[base + t] : -3.402823466e38f;
  int   ri = t;
  nid[t] = -1;
  cnt[t] = 0;

  #pragma unroll
  for (int size = 2; size <= 1024; size <<= 1) {
    for (int stride = size >> 1; stride >= 64; stride >>= 1) {
      key[t] = rk; idxs[t] = ri;
      __syncthreads();
      float km = key[t ^ stride];
      int   im = idxs[t ^ stride];
      __syncthreads();
      bool mf = (rk > km) || (rk == km && ri < im);
      bool desc = ((t & size) == 0);
      bool lower = ((t & stride) == 0);
      bool keep = desc ? (lower ? mf : !mf) : (lower ? !mf : mf);
      if (!keep) { rk = km; ri = im; }
    }
    for (int stride = (size >> 1) > 32 ? 32 : (size >> 1); stride >= 1; stride >>= 1) {
      float km = __shfl_xor(rk, stride);
      int   im = __shfl_xor(ri, stride);
      bool mf = (rk > km) || (rk == km && ri < im);
      bool desc = ((t & size) == 0);
      bool lower = ((t & stride) == 0);
      bool keep = desc ? (lower ? mf : !mf) : (lower ? !mf : mf);
      if (!keep) { rk = km; ri = im; }
    }
  }

  if (t < k) {
    float inv = *inv_norm_p;
    nid[ri] = t;
    sel_pos[g * k + t] = base + ri;
    sel_scale[g * k + t] = tanhf(rk * inv);
  }
  if (!build_next) return;
  __syncthreads();
  const int e0 = g * EPG;
  const int newBase = g * k;
  int lns[8], lnd[8];
  #pragma unroll
  for (int i = 0; i < 8; ++i) {
    int e = e0 + t + i * 1024;
    int sv = ein_src[e];
    int ns = -1, nd = -1;
    if (sv >= 0) {
      int dv = ein_dst[e];
      ns = nid[sv - base];
      nd = nid[dv - base];
      if (ns < 0 || nd < 0) ns = -1;
    }
    lns[i] = ns; lnd[i] = nd;
    if (write_eout) {
      eout_src[e] = (ns >= 0) ? (newBase + ns) : -1;
      eout_dst[e] = (ns >= 0) ? (newBase + nd) : -1;
    }
    if (ns >= 0) atomicAdd(&cnt[nd], 1);
  }
  __syncthreads();
  const int lane = t & 63, w = t >> 6;
  int cv = cnt[t];
  int x = cv;
  #pragma unroll
  for (int off = 1; off < 64; off <<= 1) {
    int y = __shfl_up(x, off);
    if (lane >= off) x += y;
  }
  if (lane == 63) wsum[w] = x;
  __syncthreads();
  if (t < 16) {
    int v = wsum[t];
    #pragma unroll
    for (int off2 = 1; off2 < 16; off2 <<= 1) {
      int y = __shfl_up(v, off2);
      if (t >= off2) v += y;
    }
    wsum[t] = v;
  }
  __syncthreads();
  int incl = x + (w ? wsum[w - 1] : 0);
  int excl = incl - cv;
  cur[t] = excl;
  off_g[g * 1025 + t] = excl;
  if (t < k) c_out[newBase + t] = (float)cv;
  __syncthreads();
  int* elp = elist_g + g * EPG;
  #pragma unroll
  for (int i = 0; i < 8; ++i) {
    if (lns[i] >= 0) {
      int pos = atomicAdd(&cur[lnd[i]], 1);
      elp[pos] = newBase + lns[i];
    }
  }
}

// ------- fused pool + readout partial (bf16 rows): block=(graph,chunk) ----
__global__ __launch_bounds__(256) void k_pool_part(const unsigned short* __restrict__ hbf,
    const int* __restrict__ sel_pos, const float* __restrict__ sel_scale, int k,
    unsigned short* __restrict__ xbf, float* __restrict__ pmax, float* __restrict__ psum)
{
  __shared__ float4 smx[256], ssm[256];
  const int b  = blockIdx.x >> 4;
  const int ch = blockIdx.x & (RCHUNK - 1);
  const int rpc = (k + RCHUNK - 1) / RCHUNK;
  const int r0 = ch * rpc;
  const int r1 = min(k, r0 + rpc);
  const int d4  = threadIdx.x & 31;
  const int sub = threadIdx.x >> 5;
  const float NEG = -3.402823466e38f;
  const uint2* hb2 = (const uint2*)hbf;
  uint2* xb2 = (uint2*)xbf;
  float4 mx = {NEG, NEG, NEG, NEG};
  float4 sm = {0.f, 0.f, 0.f, 0.f};
  for (int r = r0 + sub; r < r1; r += 8) {
    int j = b * k + r;
    float scv = sel_scale[j];
    uint2 u = hb2[(size_t)sel_pos[j] * 32 + d4];
    float4 v;
    v.x = bf_lo(u.x) * scv; v.y = bf_hi(u.x) * scv;
    v.z = bf_lo(u.y) * scv; v.w = bf_hi(u.y) * scv;
    uint2 o;
    o.x = pack2bf(v.x, v.y);
    o.y = pack2bf(v.z, v.w);
    xb2[(size_t)j * 32 + d4] = o;
    v.x = bf_lo(o.x); v.y = bf_hi(o.x); v.z = bf_lo(o.y); v.w = bf_hi(o.y);
    mx.x = fmaxf(mx.x, v.x); mx.y = fmaxf(mx.y, v.y);
    mx.z = fmaxf(mx.z, v.z); mx.w = fmaxf(mx.w, v.w);
    sm.x += v.x; sm.y += v.y; sm.z += v.z; sm.w += v.w;
  }
  smx[threadIdx.x] = mx; ssm[threadIdx.x] = sm;
  __syncthreads();
  if (sub < 4) {
    #pragma unroll
    for (int step = 4; step >= 1; step >>= 1) {
      if (sub < step) {
        float4 m2 = smx[(sub + step) * 32 + d4];
        float4 s2 = ssm[(sub + step) * 32 + d4];
        mx = smx[sub * 32 + d4]; sm = ssm[sub * 32 + d4];
        mx.x = fmaxf(mx.x, m2.x); mx.y = fmaxf(mx.y, m2.y);
        mx.z = fmaxf(mx.z, m2.z); mx.w = fmaxf(mx.w, m2.w);
        sm.x += s2.x; sm.y += s2.y; sm.z += s2.z; sm.w += s2.w;
        smx[sub * 32 + d4] = mx; ssm[sub * 32 + d4] = sm;
      }
      __syncthreads();
    }
  }
  if (sub == 0) {
    int o = (b * RCHUNK + ch) * 32 + d4;
    ((float4*)pmax)[o] = smx[d4];
    ((float4*)psum)[o] = ssm[d4];
  }
}

// ------- merged readout: combine all 3 stages' partials into rdT ----------
__global__ __launch_bounds__(128) void k_readout_final3(
    const float* __restrict__ pmax, const float* __restrict__ psum,
    int k0, int k1, int k2, float* __restrict__ rdT)
{
  int b = blockIdx.x, d = threadIdx.x;
  const int ks[3] = {k0, k1, k2};
  float tmx = 0.f, tmn = 0.f;
  #pragma unroll
  for (int s = 0; s < 3; ++s) {
    const float* pm = pmax + (size_t)s * PSTRIDE;
    const float* ps = psum + (size_t)s * PSTRIDE;
    float mx = -3.402823466e38f, sm = 0.f;
    #pragma unroll
    for (int c = 0; c < RCHUNK; ++c) {
      int o = (b * RCHUNK + c) * 128 + d;
      mx = fmaxf(mx, pm[o]);
      sm += ps[o];
    }
    tmx += mx;
    tmn += sm / (float)ks[s];
  }
  rdT[d * 64 + b] = tmx;
  rdT[(128 + d) * 64 + b] = tmn;
}

// ------- MLP fc1 + BN1 + relu: 16 blocks, lane=graph, wave=feature --------
__global__ __launch_bounds__(512) void k_mlp_fc1(const float* __restrict__ rdT,
    const float* __restrict__ fc1_w, const float* __restrict__ fc1_b,
    const float* __restrict__ g1, const float* __restrict__ be1,
    float* __restrict__ y1n)
{
  __shared__ float W[8 * 256];
  __shared__ float R[256 * 64];
  const int t = threadIdx.x, b = blockIdx.x;
  ((float4*)W)[t] = ((const float4*)(fc1_w + (size_t)b * 8 * 256))[t];
  #pragma unroll
  for (int i = 0; i < 8; ++i)
    ((float4*)R)[t + i * 512] = ((const float4*)rdT)[t + i * 512];
  __syncthreads();
  const int g = t & 63, w = t >> 6;
  const float* wrow = W + w * 256;
  float acc = 0.f;
  #pragma unroll 4
  for (int k = 0; k < 256; ++k) acc += R[k * 64 + g] * wrow[k];
  int f = b * 8 + w;
  float y = acc + fc1_b[f];
  float s = y, s2 = y * y;
  #pragma unroll
  for (int off = 32; off; off >>= 1) {
    s  += __shfl_xor(s,  off);
    s2 += __shfl_xor(s2, off);
  }
  float mu = s * 0.015625f;
  float var = s2 * 0.015625f - mu * mu;
  float inv = 1.0f / sqrtf(var + 1e-5f);
  y1n[f * 64 + g] = fmaxf((y - mu) * inv * g1[f] + be1[f], 0.f);
}

// ------- MLP rest: fc2 + BN2 + relu + lin + sigmoid (1 block) -------------
__global__ __launch_bounds__(1024) void k_mlp_rest(const float* __restrict__ y1n,
    const float* __restrict__ fc2_w, const float* __restrict__ fc2_b,
    const float* __restrict__ g2, const float* __restrict__ be2,
    const float* __restrict__ lin_w, const float* __restrict__ lin_b,
    float* __restrict__ out)
{
  __shared__ float W2[64 * 128];
  __shared__ float Y[128 * 64];
  __shared__ float part[16 * 64];
  const int t = threadIdx.x;
  #pragma unroll
  for (int i = 0; i < 2; ++i) {
    ((float4*)W2)[t + i * 1024] = ((const float4*)fc2_w)[t + i * 1024];
    ((float4*)Y) [t + i * 1024] = ((const float4*)y1n)[t + i * 1024];
  }
  __syncthreads();
  const int g = t & 63, w = t >> 6;
  float acc2[4] = {0.f, 0.f, 0.f, 0.f};
  const float* w20 = W2 + (w * 4 + 0) * 128;
  const float* w21 = W2 + (w * 4 + 1) * 128;
  const float* w22 = W2 + (w * 4 + 2) * 128;
  const float* w23 = W2 + (w * 4 + 3) * 128;
  #pragma unroll 4
  for (int k = 0; k < 128; ++k) {
    float yv = Y[k * 64 + g];
    acc2[0] += yv * w20[k];
    acc2[1] += yv * w21[k];
    acc2[2] += yv * w22[k];
    acc2[3] += yv * w23[k];
  }
  float pp = 0.f;
  #pragma unroll
  for (int j = 0; j < 4; ++j) {
    int m = w * 4 + j;
    float y = acc2[j] + fc2_b[m];
    float s = y, s2 = y * y;
    #pragma unroll
    for (int off = 32; off; off >>= 1) {
      s  += __shfl_xor(s,  off);
      s2 += __shfl_xor(s2, off);
    }
    float mu = s * 0.015625f;
    float var = s2 * 0.015625f - mu * mu;
    float inv = 1.0f / sqrtf(var + 1e-5f);
    float yn = fmaxf((y - mu) * inv * g2[m] + be2[m], 0.f);
    pp += yn * lin_w[m];
  }
  part[w * 64 + g] = pp;
  __syncthreads();
  if (w == 0) {
    float a = lin_b[0];
    #pragma unroll
    for (int c = 0; c < 16; ++c) a += part[c * 64 + g];
    out[g] = 1.0f / (1.0f + expf(-a));
  }
}

extern "C" void kernel_launch(void* const* d_in, const int* in_sizes, int n_in,
                              void* d_out, int out_size, void* d_ws, size_t ws_size,
                              hipStream_t stream) {
  const int*   node_idx = (const int*)  d_in[0];
  const int*   edge_idx = (const int*)  d_in[1];
  const float* emb      = (const float*)d_in[2];
  const float* w1l      = (const float*)d_in[3];
  const float* b1l      = (const float*)d_in[4];
  const float* w1r      = (const float*)d_in[5];
  const float* pool_w   = (const float*)d_in[6];
  const float* w2l      = (const float*)d_in[7];
  const float* b2l      = (const float*)d_in[8];
  const float* w2r      = (const float*)d_in[9];
  const float* fc1_w    = (const float*)d_in[10];
  const float* fc1_b    = (const float*)d_in[11];
  const float* bn1_g    = (const float*)d_in[12];
  const float* bn1_b    = (const float*)d_in[13];
  const float* fc2_w    = (const float*)d_in[14];
  const float* fc2_b    = (const float*)d_in[15];
  const float* bn2_g    = (const float*)d_in[16];
  const float* bn2_b    = (const float*)d_in[17];
  const float* lin_w    = (const float*)d_in[18];
  const float* lin_b    = (const float*)d_in[19];
  float* out = (float*)d_out;

  char* p = (char*)d_ws;
  auto alloc = [&](size_t bytes) -> void* {
    void* r = (void*)p;
    p += (bytes + 255) & ~(size_t)255;
    return r;
  };
  unsigned short* x_bf = (unsigned short*)alloc((size_t)NNODE * DIM * 2);
  unsigned short* h_bf = (unsigned short*)alloc((size_t)NNODE * DIM * 2);
  float* c_buf     = (float*)alloc((size_t)NNODE * 4);
  float* score     = (float*)alloc((size_t)NNODE * 4);
  int*   sel_pos   = (int*)  alloc((size_t)NGRAPH * 820 * 4);
  float* sel_scale = (float*)alloc((size_t)NGRAPH * 820 * 4);
  int*   src_cur   = (int*)  alloc((size_t)NEDGE * 4);
  int*   dst_cur   = (int*)  alloc((size_t)NEDGE * 4);
  int*   off_g     = (int*)  alloc((size_t)NGRAPH * 1025 * 4);
  int*   elist_g   = (int*)  alloc((size_t)NGRAPH * EPG * 4);
  float* rdT       = (float*)alloc((size_t)256 * 64 * 4);
  short* whiF      = (short*)alloc((size_t)2 * 32768 * 2);
  short* wloF      = (short*)alloc((size_t)2 * 32768 * 2);
  float* y1n       = (float*)alloc((size_t)128 * 64 * 4);
  float* pmax      = (float*)alloc(PSTRIDE * 3 * 4);
  float* psum      = (float*)alloc(PSTRIDE * 3 * 4);
  float* inv_norm  = (float*)alloc(256);

  k_gather<<<NNODE * 32 / 256, 256, 0, stream>>>(emb, node_idx, x_bf);
  k_norm<<<1, 64, 0, stream>>>(pool_w, inv_norm);
  k_prep_wfrag<<<256, 256, 0, stream>>>(w1l, w1r, w2l, w2r, whiF, wloF);
  k_csr0<<<NGRAPH, 1024, 0, stream>>>(edge_idx, off_g, elist_g, c_buf);

  const int Ks[3] = {820, 656, 525};
  int npg = NPG0;
  for (int stage = 0; stage < 3; ++stage) {
    const short* whi_s = whiF + (stage ? 32768 : 0);
    const short* wlo_s = wloF + (stage ? 32768 : 0);
    const float* bl    = stage ? b2l : b1l;
    int k = Ks[stage];
    int slices = (npg + AROWS - 1) / AROWS;

    k_agg_gemm<<<slices * 64, 128, 0, stream>>>(off_g, elist_g, x_bf, h_bf,
                                                whi_s, wlo_s, bl, pool_w,
                                                score, npg);
    const int* ein_s = (stage == 0) ? edge_idx          : src_cur;
    const int* ein_d = (stage == 0) ? (edge_idx + NEDGE) : dst_cur;
    k_topk_fused<<<NGRAPH, 1024, 0, stream>>>(score, inv_norm, npg, k,
        sel_pos, sel_scale,
        (stage < 2) ? 1 : 0, (stage == 0) ? 1 : 0,
        ein_s, ein_d, src_cur, dst_cur,
        off_g, elist_g, c_buf);
    k_pool_part<<<NGRAPH * RCHUNK, 256, 0, stream>>>(h_bf, sel_pos, sel_scale, k,
        x_bf, pmax + (size_t)stage * PSTRIDE, psum + (size_t)stage * PSTRIDE);
    npg = k;
  }

  k_readout_final3<<<NGRAPH, 128, 0, stream>>>(pmax, psum, Ks[0], Ks[1], Ks[2], rdT);
  k_mlp_fc1<<<16, 512, 0, stream>>>(rdT, fc1_w, fc1_b, bn1_g, bn1_b, y1n);
  k_mlp_rest<<<1, 1024, 0, stream>>>(y1n, fc2_w, fc2_b, bn2_g, bn2_b,
                                     lin_w, lin_b, out);
}

// Round 18
// 249.588 us; speedup vs baseline: 1.1285x; 1.1285x over previous
//
#include <hip/hip_runtime.h>
#include <hip/hip_bf16.h>
#include <cstdint>
#include <cstddef>

#define NGRAPH 64
#define NPG0   1024
#define NNODE  65536     // NGRAPH*NPG0
#define NEDGE  524288
#define EPG    8192      // NEDGE/NGRAPH
#define DIM    128
#define RCHUNK 16        // readout partial chunks per graph
#define PSTRIDE ((size_t)NGRAPH * RCHUNK * 128)
#define AROWS  32        // rows per k_agg_gemm block

typedef __attribute__((ext_vector_type(8))) short short8v;   // 8 bf16
typedef __attribute__((ext_vector_type(4))) float f32x4;

__device__ __forceinline__ unsigned bf16rne(float f) {
  unsigned u = __float_as_uint(f);
  return (u + 0x7FFFu + ((u >> 16) & 1u)) >> 16;
}
__device__ __forceinline__ unsigned pack2bf(float a, float b) {
  return bf16rne(a) | (bf16rne(b) << 16);
}
__device__ __forceinline__ float bf_lo(unsigned u) { return __uint_as_float(u << 16); }
__device__ __forceinline__ float bf_hi(unsigned u) { return __uint_as_float(u & 0xffff0000u); }

__device__ __forceinline__ void add8(float* a, uint4 u) {
  a[0] += bf_lo(u.x); a[1] += bf_hi(u.x);
  a[2] += bf_lo(u.y); a[3] += bf_hi(u.y);
  a[4] += bf_lo(u.z); a[5] += bf_hi(u.z);
  a[6] += bf_lo(u.w); a[7] += bf_hi(u.w);
}

// ---------------- gather x_bf = bf16(emb[node_idx]) ----------------
__global__ __launch_bounds__(256) void k_gather(const float* __restrict__ emb,
    const int* __restrict__ nid, unsigned short* __restrict__ xbf)
{
  int tid = blockIdx.x * 256 + threadIdx.x;
  int i = tid >> 5, lane = tid & 31;
  int row = nid[i];
  float4 v = ((const float4*)(emb + (size_t)row * DIM))[lane];
  uint2 u;
  u.x = pack2bf(v.x, v.y);
  u.y = pack2bf(v.z, v.w);
  ((uint2*)xbf)[(size_t)i * 32 + lane] = u;
}

// ---------------- 1/||pool_w|| ----------------
__global__ __launch_bounds__(64) void k_norm(const float* __restrict__ pw,
    float* __restrict__ inv_norm)
{
  int t = threadIdx.x;
  float a = pw[t], b = pw[t + 64];
  float v = a * a + b * b;
  for (int off = 32; off; off >>= 1) v += __shfl_xor(v, off);
  if (t == 0) *inv_norm = 1.0f / sqrtf(v);
}

// ------- pre-swizzle weights into MFMA B-fragment layout, bf16 hi/lo ------
__global__ __launch_bounds__(256) void k_prep_wfrag(
    const float* __restrict__ w1l, const float* __restrict__ w1r,
    const float* __restrict__ w2l, const float* __restrict__ w2r,
    short* __restrict__ whiF, short* __restrict__ wloF)
{
  int id = blockIdx.x * 256 + threadIdx.x;    // 0..65535 (2 sets x 32768)
  int set = id >> 15;
  int r = id & 32767;
  int j  = r & 7;
  int l  = (r >> 3) & 63;
  int nt = (r >> 9) & 7;
  int kk = r >> 12;
  int k = kk * 32 + ((l >> 4) & 3) * 8 + j;
  int n = nt * 16 + (l & 15);
  const float* wl = set ? w2l : w1l;
  const float* wr = set ? w2r : w1r;
  float w = (k < 128) ? wl[n * 128 + k] : wr[n * 128 + (k - 128)];
  unsigned hb = bf16rne(w);
  float hif = __uint_as_float(hb << 16);
  unsigned lb = bf16rne(w - hif);
  whiF[id] = (short)hb;
  wloF[id] = (short)lb;
}

// ---------------- stage-0 CSR build straight from edge_idx ----------------
__global__ __launch_bounds__(1024) void k_csr0(const int* __restrict__ ei,
    int* __restrict__ off_g, int* __restrict__ elist_g, float* __restrict__ c_out)
{
  __shared__ int cnt[1024];
  __shared__ int cur[1024];
  __shared__ int wsum[16];
  const int t = threadIdx.x, g = blockIdx.x;
  const int nodeBase = g * NPG0;
  const int e0 = g * EPG;
  cnt[t] = 0;
  __syncthreads();
  int sv8[8], dl8[8];
  #pragma unroll
  for (int i = 0; i < 8; ++i) {
    int e = e0 + t + i * 1024;
    sv8[i] = ei[e];
    dl8[i] = ei[NEDGE + e] - nodeBase;
    atomicAdd(&cnt[dl8[i]], 1);
  }
  __syncthreads();
  const int lane = t & 63, w = t >> 6;
  int cv = cnt[t];
  int x = cv;
  #pragma unroll
  for (int off = 1; off < 64; off <<= 1) {
    int y = __shfl_up(x, off);
    if (lane >= off) x += y;
  }
  if (lane == 63) wsum[w] = x;
  __syncthreads();
  if (t < 16) {
    int v = wsum[t];
    #pragma unroll
    for (int off2 = 1; off2 < 16; off2 <<= 1) {
      int y = __shfl_up(v, off2);
      if (t >= off2) v += y;
    }
    wsum[t] = v;
  }
  __syncthreads();
  int incl = x + (w ? wsum[w - 1] : 0);
  int excl = incl - cv;
  cur[t] = excl;
  int* offp = off_g + g * 1025;
  offp[t] = excl;
  if (t == 1023) offp[1024] = incl;
  c_out[nodeBase + t] = (float)cv;
  __syncthreads();
  int* elp = elist_g + g * EPG;
  #pragma unroll
  for (int i = 0; i < 8; ++i) {
    int pos = atomicAdd(&cur[dl8[i]], 1);
    elp[pos] = sv8[i];
  }
}

// ------- FUSED aggregate + MFMA SAGE layer (bf16, 2 rows per load) --------
// blockIdx = slice*64 + g ; 32 rows / 128 threads.
// Phase A: one uint4x32-lane load fetches TWO 256B bf16 rows (lanes 0-15 =
// even edge, 16-31 = odd edge); halves merged by shfl_xor(16) at the end.
__global__ __launch_bounds__(128) void k_agg_gemm(
    const int* __restrict__ off_g, const int* __restrict__ elist_g,
    const unsigned short* __restrict__ xbf, unsigned short* __restrict__ hbf,
    const short* __restrict__ whiF, const short* __restrict__ wloF,
    const float* __restrict__ bl, const float* __restrict__ pw,
    float* __restrict__ score, int npg)
{
  __shared__ float sA[AROWS * 128];   // 16 KB f32 aggregate tile, XOR swizzle
  __shared__ float cntA[AROWS];
  const int g     = blockIdx.x & 63;
  const int slice = blockIdx.x >> 6;
  const int nodeBase = g * npg;
  const int vbase = slice * AROWS;
  const int t = threadIdx.x;
  float4* sA4 = (float4*)sA;
  const uint4* xb4 = (const uint4*)xbf;   // 16 uint4 per row

  // ---- phase A ----
  {
    const int gr = t >> 5, l32 = t & 31;
    const int lh = l32 & 15;           // uint4 slot within row
    const int half = l32 >> 4;         // 0: even edge, 1: odd edge
    const int* off = off_g + g * 1025;
    const int* el  = elist_g + g * EPG;
    #pragma unroll
    for (int ip = 0; ip < 4; ++ip) {
      const int vbA = gr * 8 + ip * 2, vbB = vbA + 1;
      const int vA = vbase + vbA, vB = vbase + vbB;
      float accA[8] = {0,0,0,0,0,0,0,0}, accB[8] = {0,0,0,0,0,0,0,0};
      int eA = 0, endA = 0, eB = 0, endB = 0;
      if (vA < npg) { eA = off[vA]; endA = off[vA + 1]; }
      if (vB < npg) { eB = off[vB]; endB = off[vB + 1]; }
      const int cnA = endA - eA, cnB = endB - eB;
      // 4 independent 512B loads in flight (2 per dest row)
      while (eA + 4 <= endA && eB + 4 <= endB) {
        int ia0 = el[eA + half],     ia1 = el[eA + 2 + half];
        int ib0 = el[eB + half],     ib1 = el[eB + 2 + half];
        uint4 ua0 = xb4[(size_t)ia0 * 16 + lh];
        uint4 ua1 = xb4[(size_t)ia1 * 16 + lh];
        uint4 ub0 = xb4[(size_t)ib0 * 16 + lh];
        uint4 ub1 = xb4[(size_t)ib1 * 16 + lh];
        add8(accA, ua0); add8(accA, ua1);
        add8(accB, ub0); add8(accB, ub1);
        eA += 4; eB += 4;
      }
      // drain A: pairs then single
      while (eA + 2 <= endA) {
        uint4 u = xb4[(size_t)el[eA + half] * 16 + lh];
        add8(accA, u);
        eA += 2;
      }
      if (eA < endA && half == 0) {
        uint4 u = xb4[(size_t)el[eA] * 16 + lh];
        add8(accA, u);
      }
      // drain B
      while (eB + 2 <= endB) {
        uint4 u = xb4[(size_t)el[eB + half] * 16 + lh];
        add8(accB, u);
        eB += 2;
      }
      if (eB < endB && half == 0) {
        uint4 u = xb4[(size_t)el[eB] * 16 + lh];
        add8(accB, u);
      }
      // merge even/odd halves
      #pragma unroll
      for (int j = 0; j < 8; ++j) {
        accA[j] += __shfl_xor(accA[j], 16);
        accB[j] += __shfl_xor(accB[j], 16);
      }
      if (half == 0) {
        float4 a0 = {accA[0], accA[1], accA[2], accA[3]};
        float4 a1 = {accA[4], accA[5], accA[6], accA[7]};
        float4 b0 = {accB[0], accB[1], accB[2], accB[3]};
        float4 b1 = {accB[4], accB[5], accB[6], accB[7]};
        sA4[vbA * 32 + ((2 * lh + 0) ^ (vbA & 7))] = a0;
        sA4[vbA * 32 + ((2 * lh + 1) ^ (vbA & 7))] = a1;
        sA4[vbB * 32 + ((2 * lh + 0) ^ (vbB & 7))] = b0;
        sA4[vbB * 32 + ((2 * lh + 1) ^ (vbB & 7))] = b1;
      }
      if (l32 == 0) { cntA[vbA] = (float)cnA; cntA[vbB] = (float)cnB; }
    }
  }
  __syncthreads();

  // ---- phase B: MFMA GEMM (2 waves x 16 rows) ----
  const int wv = t >> 6, l = t & 63;
  const int lrow = l & 15, lk = l >> 4;      // lk 0..3
  const int rb = wv * 16;
  const int rowb = rb + lrow;                // 0..31
  const int rsw = rowb & 7;
  const int rowg = nodeBase + min(vbase + rowb, npg - 1);
  const float invc = 1.0f / fmaxf(cntA[rowb], 1.0f);
  f32x4 acc[8];
  #pragma unroll
  for (int nt = 0; nt < 8; ++nt) acc[nt] = (f32x4){0.f, 0.f, 0.f, 0.f};
  const float4* sArow = sA4 + rowb * 32;
  const uint4* xrow4 = (const uint4*)xbf + (size_t)rowg * 16;   // 16 uint4/row
  const short8v* bh = (const short8v*)whiF;
  const short8v* bo = (const short8v*)wloF;

  #pragma unroll
  for (int kk = 0; kk < 8; ++kk) {
    short8v ahi, alo;
    bool self16 = (kk >= 4);     // self term is exactly bf16 -> skip alo
    if (!self16) {
      int sbase = kk * 8 + lk * 2;
      float4 a0 = sArow[(sbase + 0) ^ rsw];
      float4 a1 = sArow[(sbase + 1) ^ rsw];
      float av[8] = { a0.x * invc, a0.y * invc, a0.z * invc, a0.w * invc,
                      a1.x * invc, a1.y * invc, a1.z * invc, a1.w * invc };
      #pragma unroll
      for (int j = 0; j < 8; ++j) {
        unsigned hb2 = bf16rne(av[j]);
        float hif = __uint_as_float(hb2 << 16);
        ahi[j] = (short)hb2;
        alo[j] = (short)bf16rne(av[j] - hif);
      }
    } else {
      uint4 u = xrow4[(kk - 4) * 4 + lk];
      ahi[0] = (short)(u.x & 0xffff); ahi[1] = (short)(u.x >> 16);
      ahi[2] = (short)(u.y & 0xffff); ahi[3] = (short)(u.y >> 16);
      ahi[4] = (short)(u.z & 0xffff); ahi[5] = (short)(u.z >> 16);
      ahi[6] = (short)(u.w & 0xffff); ahi[7] = (short)(u.w >> 16);
    }
    #pragma unroll
    for (int nt = 0; nt < 8; ++nt) {
      int fi = (kk * 8 + nt) * 64 + l;
      short8v bhi = bh[fi];
      short8v blo = bo[fi];
      acc[nt] = __builtin_amdgcn_mfma_f32_16x16x32_bf16(ahi, bhi, acc[nt], 0, 0, 0);
      if (!self16)
        acc[nt] = __builtin_amdgcn_mfma_f32_16x16x32_bf16(alo, bhi, acc[nt], 0, 0, 0);
      acc[nt] = __builtin_amdgcn_mfma_f32_16x16x32_bf16(ahi, blo, acc[nt], 0, 0, 0);
    }
  }

  float sp0 = 0.f, sp1 = 0.f, sp2 = 0.f, sp3 = 0.f;
  const int mbv = vbase + rb + lk * 4;
  #pragma unroll
  for (int nt = 0; nt < 8; ++nt) {
    int col = nt * 16 + lrow;
    float bb = bl[col], pv = pw[col];
    float h0 = fmaxf(acc[nt][0] + bb, 0.f);
    float h1 = fmaxf(acc[nt][1] + bb, 0.f);
    float h2 = fmaxf(acc[nt][2] + bb, 0.f);
    float h3 = fmaxf(acc[nt][3] + bb, 0.f);
    if (mbv + 0 < npg) hbf[(size_t)(nodeBase + mbv + 0) * DIM + col] = (unsigned short)bf16rne(h0);
    if (mbv + 1 < npg) hbf[(size_t)(nodeBase + mbv + 1) * DIM + col] = (unsigned short)bf16rne(h1);
    if (mbv + 2 < npg) hbf[(size_t)(nodeBase + mbv + 2) * DIM + col] = (unsigned short)bf16rne(h2);
    if (mbv + 3 < npg) hbf[(size_t)(nodeBase + mbv + 3) * DIM + col] = (unsigned short)bf16rne(h3);
    sp0 += h0 * pv; sp1 += h1 * pv; sp2 += h2 * pv; sp3 += h3 * pv;
  }
  #pragma unroll
  for (int off = 1; off <= 8; off <<= 1) {
    sp0 += __shfl_xor(sp0, off);
    sp1 += __shfl_xor(sp1, off);
    sp2 += __shfl_xor(sp2, off);
    sp3 += __shfl_xor(sp3, off);
  }
  if (lrow == 0) {
    if (mbv + 0 < npg) score[nodeBase + mbv + 0] = sp0;
    if (mbv + 1 < npg) score[nodeBase + mbv + 1] = sp1;
    if (mbv + 2 < npg) score[nodeBase + mbv + 2] = sp2;
    if (mbv + 3 < npg) score[nodeBase + mbv + 3] = sp3;
  }
}

// ------- fused: shuffle-bitonic top-k + relabel + build next CSR ----------
__global__ __launch_bounds__(1024) void k_topk_fused(
    const float* __restrict__ score, const float* __restrict__ inv_norm_p,
    int npg, int k, int* __restrict__ sel_pos, float* __restrict__ sel_scale,
    int build_next, int write_eout,
    const int* __restrict__ ein_src, const int* __restrict__ ein_dst,
    int* __restrict__ eout_src, int* __restrict__ eout_dst,
    int* __restrict__ off_g, int* __restrict__ elist_g, float* __restrict__ c_out)
{
  __shared__ float key[1024];
  __shared__ int   idxs[1024];
  __shared__ int   nid[1024];
  __shared__ int   cnt[1024];
  __shared__ int   cur[1024];
  __shared__ int   wsum[16];
  const int t = threadIdx.x, g = blockIdx.x;
  const int base = g * npg;
  float rk = (t < npg) ? score[base + t] : -3.402823466e38f;
  int   ri = t;
  nid[t] = -1;
  cnt[t] = 0;

  #pragma unroll
  for (int size = 2; size <= 1024; size <<= 1) {
    for (int stride = size >> 1; stride >= 64; stride >>= 1) {
      key[t] = rk; idxs[t] = ri;
      __syncthreads();
      float km = key[t ^ stride];
      int   im = idxs[t ^ stride];
      __syncthreads();
      bool mf = (rk > km) || (rk == km && ri < im);
      bool desc = ((t & size) == 0);
      bool lower = ((t & stride) == 0);
      bool keep = desc ? (lower ? mf : !mf) : (lower ? !mf : mf);
      if (!keep) { rk = km; ri = im; }
    }
    for (int stride = (size >> 1) > 32 ? 32 : (size >> 1); stride >= 1; stride >>= 1) {
      float km = __shfl_xor(rk, stride);
      int   im = __shfl_xor(ri, stride);
      bool mf = (rk > km) || (rk == km && ri < im);
      bool desc = ((t & size) == 0);
      bool lower = ((t & stride) == 0);
      bool keep = desc ? (lower ? mf : !mf) : (lower ? !mf : mf);
      if (!keep) { rk = km; ri = im; }
    }
  }

  if (t < k) {
    float inv = *inv_norm_p;
    nid[ri] = t;
    sel_pos[g * k + t] = base + ri;
    sel_scale[g * k + t] = tanhf(rk * inv);
  }
  if (!build_next) return;
  __syncthreads();
  const int e0 = g * EPG;
  const int newBase = g * k;
  int lns[8], lnd[8];
  #pragma unroll
  for (int i = 0; i < 8; ++i) {
    int e = e0 + t + i * 1024;
    int sv = ein_src[e];
    int ns = -1, nd = -1;
    if (sv >= 0) {
      int dv = ein_dst[e];
      ns = nid[sv - base];
      nd = nid[dv - base];
      if (ns < 0 || nd < 0) ns = -1;
    }
    lns[i] = ns; lnd[i] = nd;
    if (write_eout) {
      eout_src[e] = (ns >= 0) ? (newBase + ns) : -1;
      eout_dst[e] = (ns >= 0) ? (newBase + nd) : -1;
    }
    if (ns >= 0) atomicAdd(&cnt[nd], 1);
  }
  __syncthreads();
  const int lane = t & 63, w = t >> 6;
  int cv = cnt[t];
  int x = cv;
  #pragma unroll
  for (int off = 1; off < 64; off <<= 1) {
    int y = __shfl_up(x, off);
    if (lane >= off) x += y;
  }
  if (lane == 63) wsum[w] = x;
  __syncthreads();
  if (t < 16) {
    int v = wsum[t];
    #pragma unroll
    for (int off2 = 1; off2 < 16; off2 <<= 1) {
      int y = __shfl_up(v, off2);
      if (t >= off2) v += y;
    }
    wsum[t] = v;
  }
  __syncthreads();
  int incl = x + (w ? wsum[w - 1] : 0);
  int excl = incl - cv;
  cur[t] = excl;
  off_g[g * 1025 + t] = excl;
  if (t < k) c_out[newBase + t] = (float)cv;
  __syncthreads();
  int* elp = elist_g + g * EPG;
  #pragma unroll
  for (int i = 0; i < 8; ++i) {
    if (lns[i] >= 0) {
      int pos = atomicAdd(&cur[lnd[i]], 1);
      elp[pos] = newBase + lns[i];
    }
  }
}

// ------- fused pool + readout partial (bf16 rows): block=(graph,chunk) ----
__global__ __launch_bounds__(256) void k_pool_part(const unsigned short* __restrict__ hbf,
    const int* __restrict__ sel_pos, const float* __restrict__ sel_scale, int k,
    unsigned short* __restrict__ xbf, float* __restrict__ pmax, float* __restrict__ psum)
{
  __shared__ float4 smx[256], ssm[256];
  const int b  = blockIdx.x >> 4;
  const int ch = blockIdx.x & (RCHUNK - 1);
  const int rpc = (k + RCHUNK - 1) / RCHUNK;
  const int r0 = ch * rpc;
  const int r1 = min(k, r0 + rpc);
  const int d4  = threadIdx.x & 31;
  const int sub = threadIdx.x >> 5;
  const float NEG = -3.402823466e38f;
  const uint2* hb2 = (const uint2*)hbf;
  uint2* xb2 = (uint2*)xbf;
  float4 mx = {NEG, NEG, NEG, NEG};
  float4 sm = {0.f, 0.f, 0.f, 0.f};
  for (int r = r0 + sub; r < r1; r += 8) {
    int j = b * k + r;
    float scv = sel_scale[j];
    uint2 u = hb2[(size_t)sel_pos[j] * 32 + d4];
    float4 v;
    v.x = bf_lo(u.x) * scv; v.y = bf_hi(u.x) * scv;
    v.z = bf_lo(u.y) * scv; v.w = bf_hi(u.y) * scv;
    uint2 o;
    o.x = pack2bf(v.x, v.y);
    o.y = pack2bf(v.z, v.w);
    xb2[(size_t)j * 32 + d4] = o;
    v.x = bf_lo(o.x); v.y = bf_hi(o.x); v.z = bf_lo(o.y); v.w = bf_hi(o.y);
    mx.x = fmaxf(mx.x, v.x); mx.y = fmaxf(mx.y, v.y);
    mx.z = fmaxf(mx.z, v.z); mx.w = fmaxf(mx.w, v.w);
    sm.x += v.x; sm.y += v.y; sm.z += v.z; sm.w += v.w;
  }
  smx[threadIdx.x] = mx; ssm[threadIdx.x] = sm;
  __syncthreads();
  if (sub < 4) {
    #pragma unroll
    for (int step = 4; step >= 1; step >>= 1) {
      if (sub < step) {
        float4 m2 = smx[(sub + step) * 32 + d4];
        float4 s2 = ssm[(sub + step) * 32 + d4];
        mx = smx[sub * 32 + d4]; sm = ssm[sub * 32 + d4];
        mx.x = fmaxf(mx.x, m2.x); mx.y = fmaxf(mx.y, m2.y);
        mx.z = fmaxf(mx.z, m2.z); mx.w = fmaxf(mx.w, m2.w);
        sm.x += s2.x; sm.y += s2.y; sm.z += s2.z; sm.w += s2.w;
        smx[sub * 32 + d4] = mx; ssm[sub * 32 + d4] = sm;
      }
      __syncthreads();
    }
  }
  if (sub == 0) {
    int o = (b * RCHUNK + ch) * 32 + d4;
    ((float4*)pmax)[o] = smx[d4];
    ((float4*)psum)[o] = ssm[d4];
  }
}

// ------- merged readout: combine all 3 stages' partials into rdT ----------
__global__ __launch_bounds__(128) void k_readout_final3(
    const float* __restrict__ pmax, const float* __restrict__ psum,
    int k0, int k1, int k2, float* __restrict__ rdT)
{
  int b = blockIdx.x, d = threadIdx.x;
  const int ks[3] = {k0, k1, k2};
  float tmx = 0.f, tmn = 0.f;
  #pragma unroll
  for (int s = 0; s < 3; ++s) {
    const float* pm = pmax + (size_t)s * PSTRIDE;
    const float* ps = psum + (size_t)s * PSTRIDE;
    float mx = -3.402823466e38f, sm = 0.f;
    #pragma unroll
    for (int c = 0; c < RCHUNK; ++c) {
      int o = (b * RCHUNK + c) * 128 + d;
      mx = fmaxf(mx, pm[o]);
      sm += ps[o];
    }
    tmx += mx;
    tmn += sm / (float)ks[s];
  }
  rdT[d * 64 + b] = tmx;
  rdT[(128 + d) * 64 + b] = tmn;
}

// ------- MLP fc1 + BN1 + relu: 16 blocks, lane=graph, wave=feature --------
__global__ __launch_bounds__(512) void k_mlp_fc1(const float* __restrict__ rdT,
    const float* __restrict__ fc1_w, const float* __restrict__ fc1_b,
    const float* __restrict__ g1, const float* __restrict__ be1,
    float* __restrict__ y1n)
{
  __shared__ float W[8 * 256];
  __shared__ float R[256 * 64];
  const int t = threadIdx.x, b = blockIdx.x;
  ((float4*)W)[t] = ((const float4*)(fc1_w + (size_t)b * 8 * 256))[t];
  #pragma unroll
  for (int i = 0; i < 8; ++i)
    ((float4*)R)[t + i * 512] = ((const float4*)rdT)[t + i * 512];
  __syncthreads();
  const int g = t & 63, w = t >> 6;
  const float* wrow = W + w * 256;
  float acc = 0.f;
  #pragma unroll 4
  for (int k = 0; k < 256; ++k) acc += R[k * 64 + g] * wrow[k];
  int f = b * 8 + w;
  float y = acc + fc1_b[f];
  float s = y, s2 = y * y;
  #pragma unroll
  for (int off = 32; off; off >>= 1) {
    s  += __shfl_xor(s,  off);
    s2 += __shfl_xor(s2, off);
  }
  float mu = s * 0.015625f;
  float var = s2 * 0.015625f - mu * mu;
  float inv = 1.0f / sqrtf(var + 1e-5f);
  y1n[f * 64 + g] = fmaxf((y - mu) * inv * g1[f] + be1[f], 0.f);
}

// ------- MLP rest: fc2 + BN2 + relu + lin + sigmoid (1 block) -------------
__global__ __launch_bounds__(1024) void k_mlp_rest(const float* __restrict__ y1n,
    const float* __restrict__ fc2_w, const float* __restrict__ fc2_b,
    const float* __restrict__ g2, const float* __restrict__ be2,
    const float* __restrict__ lin_w, const float* __restrict__ lin_b,
    float* __restrict__ out)
{
  __shared__ float W2[64 * 128];
  __shared__ float Y[128 * 64];
  __shared__ float part[16 * 64];
  const int t = threadIdx.x;
  #pragma unroll
  for (int i = 0; i < 2; ++i) {
    ((float4*)W2)[t + i * 1024] = ((const float4*)fc2_w)[t + i * 1024];
    ((float4*)Y) [t + i * 1024] = ((const float4*)y1n)[t + i * 1024];
  }
  __syncthreads();
  const int g = t & 63, w = t >> 6;
  float acc2[4] = {0.f, 0.f, 0.f, 0.f};
  const float* w20 = W2 + (w * 4 + 0) * 128;
  const float* w21 = W2 + (w * 4 + 1) * 128;
  const float* w22 = W2 + (w * 4 + 2) * 128;
  const float* w23 = W2 + (w * 4 + 3) * 128;
  #pragma unroll 4
  for (int k = 0; k < 128; ++k) {
    float yv = Y[k * 64 + g];
    acc2[0] += yv * w20[k];
    acc2[1] += yv * w21[k];
    acc2[2] += yv * w22[k];
    acc2[3] += yv * w23[k];
  }
  float pp = 0.f;
  #pragma unroll
  for (int j = 0; j < 4; ++j) {
    int m = w * 4 + j;
    float y = acc2[j] + fc2_b[m];
    float s = y, s2 = y * y;
    #pragma unroll
    for (int off = 32; off; off >>= 1) {
      s  += __shfl_xor(s,  off);
      s2 += __shfl_xor(s2, off);
    }
    float mu = s * 0.015625f;
    float var = s2 * 0.015625f - mu * mu;
    float inv = 1.0f / sqrtf(var + 1e-5f);
    float yn = fmaxf((y - mu) * inv * g2[m] + be2[m], 0.f);
    pp += yn * lin_w[m];
  }
  part[w * 64 + g] = pp;
  __syncthreads();
  if (w == 0) {
    float a = lin_b[0];
    #pragma unroll
    for (int c = 0; c < 16; ++c) a += part[c * 64 + g];
    out[g] = 1.0f / (1.0f + expf(-a));
  }
}

extern "C" void kernel_launch(void* const* d_in, const int* in_sizes, int n_in,
                              void* d_out, int out_size, void* d_ws, size_t ws_size,
                              hipStream_t stream) {
  const int*   node_idx = (const int*)  d_in[0];
  const int*   edge_idx = (const int*)  d_in[1];
  const float* emb      = (const float*)d_in[2];
  const float* w1l      = (const float*)d_in[3];
  const float* b1l      = (const float*)d_in[4];
  const float* w1r      = (const float*)d_in[5];
  const float* pool_w   = (const float*)d_in[6];
  const float* w2l      = (const float*)d_in[7];
  const float* b2l      = (const float*)d_in[8];
  const float* w2r      = (const float*)d_in[9];
  const float* fc1_w    = (const float*)d_in[10];
  const float* fc1_b    = (const float*)d_in[11];
  const float* bn1_g    = (const float*)d_in[12];
  const float* bn1_b    = (const float*)d_in[13];
  const float* fc2_w    = (const float*)d_in[14];
  const float* fc2_b    = (const float*)d_in[15];
  const float* bn2_g    = (const float*)d_in[16];
  const float* bn2_b    = (const float*)d_in[17];
  const float* lin_w    = (const float*)d_in[18];
  const float* lin_b    = (const float*)d_in[19];
  float* out = (float*)d_out;

  char* p = (char*)d_ws;
  auto alloc = [&](size_t bytes) -> void* {
    void* r = (void*)p;
    p += (bytes + 255) & ~(size_t)255;
    return r;
  };
  unsigned short* x_bf = (unsigned short*)alloc((size_t)NNODE * DIM * 2);
  unsigned short* h_bf = (unsigned short*)alloc((size_t)NNODE * DIM * 2);
  float* c_buf     = (float*)alloc((size_t)NNODE * 4);
  float* score     = (float*)alloc((size_t)NNODE * 4);
  int*   sel_pos   = (int*)  alloc((size_t)NGRAPH * 820 * 4);
  float* sel_scale = (float*)alloc((size_t)NGRAPH * 820 * 4);
  int*   src_cur   = (int*)  alloc((size_t)NEDGE * 4);
  int*   dst_cur   = (int*)  alloc((size_t)NEDGE * 4);
  int*   off_g     = (int*)  alloc((size_t)NGRAPH * 1025 * 4);
  int*   elist_g   = (int*)  alloc((size_t)NGRAPH * EPG * 4);
  float* rdT       = (float*)alloc((size_t)256 * 64 * 4);
  short* whiF      = (short*)alloc((size_t)2 * 32768 * 2);
  short* wloF      = (short*)alloc((size_t)2 * 32768 * 2);
  float* y1n       = (float*)alloc((size_t)128 * 64 * 4);
  float* pmax      = (float*)alloc(PSTRIDE * 3 * 4);
  float* psum      = (float*)alloc(PSTRIDE * 3 * 4);
  float* inv_norm  = (float*)alloc(256);

  k_gather<<<NNODE * 32 / 256, 256, 0, stream>>>(emb, node_idx, x_bf);
  k_norm<<<1, 64, 0, stream>>>(pool_w, inv_norm);
  k_prep_wfrag<<<256, 256, 0, stream>>>(w1l, w1r, w2l, w2r, whiF, wloF);
  k_csr0<<<NGRAPH, 1024, 0, stream>>>(edge_idx, off_g, elist_g, c_buf);

  const int Ks[3] = {820, 656, 525};
  int npg = NPG0;
  for (int stage = 0; stage < 3; ++stage) {
    const short* whi_s = whiF + (stage ? 32768 : 0);
    const short* wlo_s = wloF + (stage ? 32768 : 0);
    const float* bl    = stage ? b2l : b1l;
    int k = Ks[stage];
    int slices = (npg + AROWS - 1) / AROWS;

    k_agg_gemm<<<slices * 64, 128, 0, stream>>>(off_g, elist_g, x_bf, h_bf,
                                                whi_s, wlo_s, bl, pool_w,
                                                score, npg);
    const int* ein_s = (stage == 0) ? edge_idx          : src_cur;
    const int* ein_d = (stage == 0) ? (edge_idx + NEDGE) : dst_cur;
    k_topk_fused<<<NGRAPH, 1024, 0, stream>>>(score, inv_norm, npg, k,
        sel_pos, sel_scale,
        (stage < 2) ? 1 : 0, (stage == 0) ? 1 : 0,
        ein_s, ein_d, src_cur, dst_cur,
        off_g, elist_g, c_buf);
    k_pool_part<<<NGRAPH * RCHUNK, 256, 0, stream>>>(h_bf, sel_pos, sel_scale, k,
        x_bf, pmax + (size_t)stage * PSTRIDE, psum + (size_t)stage * PSTRIDE);
    npg = k;
  }

  k_readout_final3<<<NGRAPH, 128, 0, stream>>>(pmax, psum, Ks[0], Ks[1], Ks[2], rdT);
  k_mlp_fc1<<<16, 512, 0, stream>>>(rdT, fc1_w, fc1_b, bn1_g, bn1_b, y1n);
  k_mlp_rest<<<1, 1024, 0, stream>>>(y1n, fc2_w, fc2_b, bn2_g, bn2_b,
                                     lin_w, lin_b, out);
}